// Round 10
// baseline (291.367 us; speedup 1.0000x reference)
//
#include <hip/hip_runtime.h>
#include <cstdint>
#include <cstddef>

// Problem constants
constexpr int Bc = 4;
constexpr int Tc = 4096;
constexpr int Cc = 1024;
constexpr int Hc = 16;
constexpr int Dc = 64;
constexpr int Mc = Bc * Tc;        // 16384 rows
constexpr int N1c = 3 * Cc;        // 3072
constexpr int Kc = Cc;             // 1024
constexpr int KBc = Kc / 32;       // 32 k-tiles

typedef __bf16 bf16x8 __attribute__((ext_vector_type(8)));
typedef float  f32x4  __attribute__((ext_vector_type(4)));
typedef __attribute__((address_space(1))) uint32_t gu32;
typedef __attribute__((address_space(3))) uint32_t lu32;

__device__ __forceinline__ unsigned short f2bf(float f) {
    unsigned u = __float_as_uint(f);
    u += 0x7FFF + ((u >> 16) & 1);   // round-to-nearest-even (finite values)
    return (unsigned short)(u >> 16);
}

__device__ __forceinline__ void load_lds16(const void* g, void* l) {
    // wave-uniform LDS base + lane*16; per-lane global address
    __builtin_amdgcn_global_load_lds((gu32*)(uintptr_t)g, (lu32*)(uintptr_t)l, 16, 0, 0);
}

// ============ packed-fragment layout ============
// A 16(rows)x32(k) tile = 512 bf16 = 64 lanes x 8 elems, contiguous in lane order.
// lane = fq*16 + fr (fr=row&15, fq=(k&31)>>3), elem j = k&7.
// tile index: (row>>4)*KB + (k>>5).

// ---------------- merged prep: convert_x + both weight transposes -------------
__global__ __launch_bounds__(256) void prep_kernel(
    const float* __restrict__ x,    unsigned short* __restrict__ Ap,
    const float* __restrict__ Wqkv, unsigned short* __restrict__ Wqkp,
    const float* __restrict__ Wout, unsigned short* __restrict__ Wop) {
    __shared__ float tile[32][33];
    const int bid = blockIdx.x;
    const int tid = threadIdx.x;

    if (bid < 8192) {
        const int w = tid >> 6, lane = tid & 63;
        const int t = bid * 4 + w;          // tile id = mb*KB + kb
        const int mb = t >> 5, kb = t & 31;
        const int r = lane >> 2, c = lane & 3;
        const float* src = x + (size_t)(mb * 16 + r) * Kc + kb * 32 + c * 8;
        float4 f0 = *(const float4*)src;
        float4 f1 = *(const float4*)(src + 4);
        unsigned short u[8];
        u[0] = f2bf(f0.x); u[1] = f2bf(f0.y); u[2] = f2bf(f0.z); u[3] = f2bf(f0.w);
        u[4] = f2bf(f1.x); u[5] = f2bf(f1.y); u[6] = f2bf(f1.z); u[7] = f2bf(f1.w);
        *(uint4*)(Ap + (size_t)t * 512 + (c * 16 + r) * 8) = *(uint4*)u;
        return;
    }

    const float* W; unsigned short* Bp; int N; int b2;
    if (bid < 8192 + 3072) { W = Wqkv; Bp = Wqkp; N = 3072; b2 = bid - 8192; }
    else                   { W = Wout; Bp = Wop;  N = 1024; b2 = bid - 11264; }
    const int NT = N >> 5;
    const int n0 = (b2 % NT) * 32, k0 = (b2 / NT) * 32;
    const int tx = tid & 31, ty = tid >> 5;
    for (int i = ty; i < 32; i += 8)
        tile[i][tx] = W[(size_t)(k0 + i) * N + n0 + tx];
    __syncthreads();
    const int t = tid;
    const int h = t >> 7, rr = t & 127, lane = rr >> 1, half = rr & 1;
    const int fq = lane >> 4, fn = lane & 15;
    unsigned short u[4];
    #pragma unroll
    for (int j = 0; j < 4; ++j)
        u[j] = f2bf(tile[fq * 8 + half * 4 + j][h * 16 + fn]);
    size_t tileIdx = (size_t)((n0 >> 4) + h) * (Kc >> 5) + (k0 >> 5);
    *(uint2*)(Bp + tileIdx * 512 + lane * 8 + half * 4) = *(uint2*)u;
}

// ---------------- 256x256 8-wave BK=64 GEMM, 1 barrier/step, fine phases -------
// Fixes the three defects of the r1-r3 256^2 failures:
//  - BK=64: vmcnt slack ~2400 cy >> 900 cy HBM latency (r1-r3 had ~1000)
//  - fine 4-phase {4 ds_read + 16 MFMA} interleave pinned by sched_barrier(0)
//    (r1/r2 were coarse 2-phase: m196's regression case)
//  - buffer select via c*BUF arithmetic, NOT runtime array index (r3 violated
//    rule #20 -> scratch traffic)
// Sync: ONLY __syncthreads (vmcnt0+lgkmcnt0+barrier) once per K-step -- the
// r0-proven invariant; stage(k+1) issued at step top has a full step to land.
// 16 barriers total (r5: 32), 64 MFMA/barrier (r5: 32). setprio wraps each
// MFMA cluster (2 waves/SIMD at staggered phases -> T5 prerequisite exists).
// Numerics: per-accumulator k order unchanged -> bit-identical to r5.
template <bool OUT_BF16>
__global__ __launch_bounds__(512, 2) void gemm256_kernel(
    const unsigned short* __restrict__ Ap,
    const unsigned short* __restrict__ Bp,
    const float* __restrict__ bias,
    void* __restrict__ Cout,
    int M, int N, int K, int NB) {
    extern __shared__ unsigned short sm[];   // [2][A:32 | B:32][512] = 128 KB
    const int KB = K >> 5;
    const int id  = blockIdx.x;
    const int xcd = id & 7;
    const int per = id >> 3;
    const int MSTR = (M >> 8) >> 3;
    const int byl  = per & 7;
    const int bx   = (per >> 3) % NB;
    const int pass = per / (8 * NB);
    const int by   = xcd * MSTR + pass * 8 + byl;

    const int w    = threadIdx.x >> 6;
    const int lane = threadIdx.x & 63;
    const int wm   = w >> 2;     // m-half (0/1): rows wm*128..+127
    const int wn   = w & 3;      // n-quarter: cols wn*64..+63
    constexpr int BUF = 64 * 512;          // shorts per buffer

    // staging: waves 0-3 stage A slots w*8+i; waves 4-7 stage B slots (w-4)*8+i
    const bool isA = (w < 4);
    const int  w4  = isA ? w : (w - 4);
    const unsigned short* gS[8];
    unsigned short* lS[8];
    #pragma unroll
    for (int i = 0; i < 8; ++i) {
        const int t  = w4 * 8 + i;          // slot = mt*2+ks
        const int mt = t >> 1, ks = t & 1;
        const unsigned short* base = isA
            ? Ap + ((size_t)(by * 16 + mt) * KB + ks) * 512
            : Bp + ((size_t)(bx * 16 + mt) * KB + ks) * 512;
        gS[i] = base + lane * 8;
        lS[i] = sm + (isA ? 0 : 32 * 512) + t * 512;   // buffer-0 dst
    }

    // read bases (linear in lane -> conflict-free ds_read_b128)
    const unsigned short* aR = sm + (wm * 8) * 2 * 512 + lane * 8;
    const unsigned short* bR = sm + 32 * 512 + (wn * 4) * 2 * 512 + lane * 8;

    const f32x4 zero4 = {0.f, 0.f, 0.f, 0.f};
    f32x4 acc[8][4];
    #pragma unroll
    for (int i = 0; i < 8; ++i)
        #pragma unroll
        for (int j = 0; j < 4; ++j) acc[i][j] = zero4;

    const int NST = K >> 6;   // BK=64 steps
    // prologue: stage step 0 -> buf 0
    #pragma unroll
    for (int i = 0; i < 8; ++i) load_lds16(gS[i], lS[i]);
    __syncthreads();

    #pragma unroll 1
    for (int k = 0; k < NST; ++k) {
        const int c = k & 1;
        const unsigned short* aC = aR + c * BUF;
        const unsigned short* bC = bR + c * BUF;

        // stage step k+1 -> other buffer (full step of latency slack)
        if (k + 1 < NST) {
            const size_t o = (size_t)(k + 1) * 1024;   // 2 k-tiles of 512
            const int d = (c ^ 1) * BUF;
            #pragma unroll
            for (int i = 0; i < 8; ++i) load_lds16(gS[i] + o, lS[i] + d);
        }

        // B fragments for the whole step (8 x b128)
        bf16x8 bfr[8];
        #pragma unroll
        for (int nt = 0; nt < 8; ++nt)
            bfr[nt] = *(const bf16x8*)(bC + nt * 512);

        // 4 fine phases: {4 A-reads, 16 MFMA}, pinned
        #pragma unroll
        for (int p = 0; p < 4; ++p) {
            bf16x8 af[4];   // [mloc*2+ks], mloc in {0,1} -> mtile 2p+mloc
            #pragma unroll
            for (int j = 0; j < 4; ++j)
                af[j] = *(const bf16x8*)(aC + ((2 * p + (j >> 1)) * 2 + (j & 1)) * 512);
            __builtin_amdgcn_sched_barrier(0);
            __builtin_amdgcn_s_setprio(1);
            #pragma unroll
            for (int ml = 0; ml < 2; ++ml)
                #pragma unroll
                for (int ni = 0; ni < 4; ++ni) {
                    acc[2 * p + ml][ni] = __builtin_amdgcn_mfma_f32_16x16x32_bf16(
                        af[ml * 2 + 0], bfr[ni * 2 + 0], acc[2 * p + ml][ni], 0, 0, 0);
                    acc[2 * p + ml][ni] = __builtin_amdgcn_mfma_f32_16x16x32_bf16(
                        af[ml * 2 + 1], bfr[ni * 2 + 1], acc[2 * p + ml][ni], 0, 0, 0);
                }
            __builtin_amdgcn_s_setprio(0);
            __builtin_amdgcn_sched_barrier(0);
        }
        __syncthreads();   // drains this wave's stage loads + publishes buffer
    }

    // epilogue: D row = (lane>>4)*4 + reg, col = lane&15
    const int fr = lane & 15;
    const int fq = lane >> 4;
    const int m0 = by * 256 + wm * 128;
    const int n0 = bx * 256 + wn * 64;
    #pragma unroll
    for (int mi = 0; mi < 8; ++mi) {
        #pragma unroll
        for (int ni = 0; ni < 4; ++ni) {
            int row = m0 + mi * 16 + fq * 4;
            int col = n0 + ni * 16 + fr;
            float bb = bias[col];
            #pragma unroll
            for (int r = 0; r < 4; ++r) {
                float v = acc[mi][ni][r] + bb;
                if (OUT_BF16)
                    ((unsigned short*)Cout)[(size_t)(row + r) * N + col] = f2bf(v);
                else
                    ((float*)Cout)[(size_t)(row + r) * N + col] = v;
            }
        }
    }
}

// ---------------- fallback: 128x128 BK=64 GEMM (r5-verified, 102 us) ----------
template <bool OUT_BF16>
__global__ __launch_bounds__(256, 4) void lds_gemm_kernel(
    const unsigned short* __restrict__ Ap,
    const unsigned short* __restrict__ Bp,
    const float* __restrict__ bias,
    void* __restrict__ Cout,
    int M, int N, int K, int NB) {
    __shared__ unsigned short sA[16 * 512];
    __shared__ unsigned short sB[16 * 512];
    const int KB = K >> 5;
    const int MB = M >> 7;
    const int id   = blockIdx.x;
    const int xcd  = id & 7;
    const int per  = id >> 3;
    const int MSTR = MB >> 3;
    const int byl  = per & 7;
    const int bx   = (per >> 3) % NB;
    const int pass = per / (8 * NB);
    const int by   = xcd * MSTR + pass * 8 + byl;

    const int w    = threadIdx.x >> 6;
    const int lane = threadIdx.x & 63;
    const int m0 = by * 128;
    const int n0 = bx * 128;
    const int wm = (w >> 1) * 64;
    const int wn = (w & 1) * 64;

    const unsigned short* gA[4];
    const unsigned short* gB[4];
    unsigned short* lA[4];
    unsigned short* lB[4];
    #pragma unroll
    for (int i = 0; i < 4; ++i) {
        const int t  = w * 4 + i;
        const int mt = t >> 1, s = t & 1;
        gA[i] = Ap + ((size_t)(by * 8 + mt) * KB + s) * 512 + lane * 8;
        gB[i] = Bp + ((size_t)(bx * 8 + mt) * KB + s) * 512 + lane * 8;
        lA[i] = sA + t * 512;
        lB[i] = sB + t * 512;
    }

    const unsigned short* aP = sA + (wm >> 4) * 2 * 512 + lane * 8;
    const unsigned short* bP = sB + (wn >> 4) * 2 * 512 + lane * 8;

    const f32x4 zero4 = {0.f, 0.f, 0.f, 0.f};
    f32x4 acc[4][4];
    #pragma unroll
    for (int i = 0; i < 4; ++i)
        #pragma unroll
        for (int j = 0; j < 4; ++j) acc[i][j] = zero4;

    const int NIT = K >> 6;
    #pragma unroll 1
    for (int jt = 0; jt < NIT; ++jt) {
        #pragma unroll
        for (int i = 0; i < 4; ++i) {
            load_lds16(gA[i], lA[i]);
            load_lds16(gB[i], lB[i]);
        }
        #pragma unroll
        for (int i = 0; i < 4; ++i) { gA[i] += 1024; gB[i] += 1024; }
        __syncthreads();

        #pragma unroll
        for (int kk = 0; kk < 2; ++kk) {
            bf16x8 af[4], bfr[4];
            #pragma unroll
            for (int mi = 0; mi < 4; ++mi)
                af[mi]  = *(const bf16x8*)(aP + (mi * 2 + kk) * 512);
            #pragma unroll
            for (int ni = 0; ni < 4; ++ni)
                bfr[ni] = *(const bf16x8*)(bP + (ni * 2 + kk) * 512);
            #pragma unroll
            for (int mi = 0; mi < 4; ++mi)
                #pragma unroll
                for (int ni = 0; ni < 4; ++ni)
                    acc[mi][ni] = __builtin_amdgcn_mfma_f32_16x16x32_bf16(
                        af[mi], bfr[ni], acc[mi][ni], 0, 0, 0);
        }
        __syncthreads();
    }

    const int fr = lane & 15;
    const int fq = lane >> 4;
    #pragma unroll
    for (int mi = 0; mi < 4; ++mi) {
        #pragma unroll
        for (int ni = 0; ni < 4; ++ni) {
            int row = m0 + wm + mi * 16 + fq * 4;
            int col = n0 + wn + ni * 16 + fr;
            float bb = bias[col];
            #pragma unroll
            for (int r = 0; r < 4; ++r) {
                float v = acc[mi][ni][r] + bb;
                if (OUT_BF16)
                    ((unsigned short*)Cout)[(size_t)(row + r) * N + col] = f2bf(v);
                else
                    ((float*)Cout)[(size_t)(row + r) * N + col] = v;
            }
        }
    }
}

// ---------------- per-token head-axis attention (r8/r9-verified) --------------
__global__ __launch_bounds__(256) void attn_mfma_kernel(
    const unsigned short* __restrict__ qkv,
    unsigned short* __restrict__ attP) {
    __shared__ char smem[4 * 4480];
    const int w    = threadIdx.x >> 6;
    const int lane = threadIdx.x & 63;
    const int m    = lane & 15;
    const int q    = lane >> 4;
    const int row  = blockIdx.x * 4 + w;
    unsigned short* sVt = (unsigned short*)(smem + w * 4480);
    float*          sP  = (float*)(smem + w * 4480 + 3200);

    const unsigned short* src = qkv + (size_t)row * 3072;

    bf16x8 aq0 = *(const bf16x8*)(src + m * 64 + q * 8);
    bf16x8 aq1 = *(const bf16x8*)(src + m * 64 + 32 + q * 8);
    bf16x8 bk0 = *(const bf16x8*)(src + 1024 + m * 64 + q * 8);
    bf16x8 bk1 = *(const bf16x8*)(src + 1024 + m * 64 + 32 + q * 8);

    // V transpose-stage: element (g,d) at short-offset d*24 + (d>>3)*8 + g
    #pragma unroll
    for (int t = 0; t < 2; ++t) {
        int G = t * 64 + lane;
        int g = G >> 3, p = G & 7;
        uint4 vv = *(const uint4*)(src + 2048 + G * 8);
        const unsigned short* vs = (const unsigned short*)&vv;
        #pragma unroll
        for (int i = 0; i < 8; ++i)
            sVt[200 * p + 24 * i + g] = vs[i];
    }

    f32x4 s = {0.f, 0.f, 0.f, 0.f};
    s = __builtin_amdgcn_mfma_f32_16x16x32_bf16(aq0, bk0, s, 0, 0, 0);
    s = __builtin_amdgcn_mfma_f32_16x16x32_bf16(aq1, bk1, s, 0, 0, 0);

    #pragma unroll
    for (int r = 0; r < 4; ++r) {
        float t0 = s[r] * 0.125f;
        float mx = t0;
        mx = fmaxf(mx, __shfl_xor(mx, 1));
        mx = fmaxf(mx, __shfl_xor(mx, 2));
        mx = fmaxf(mx, __shfl_xor(mx, 4));
        mx = fmaxf(mx, __shfl_xor(mx, 8));
        float e = __expf(t0 - mx);
        float su = e;
        su += __shfl_xor(su, 1);
        su += __shfl_xor(su, 2);
        su += __shfl_xor(su, 4);
        su += __shfl_xor(su, 8);
        sP[(q * 4 + r) * 20 + m] = e / su;
    }
    __syncthreads();

    const float* pr = sP + m * 20 + (q & 1) * 8;
    float4 pf0 = *(const float4*)(pr);
    float4 pf1 = *(const float4*)(pr + 4);
    const bool act = (q < 2);
    union { unsigned short u[8]; bf16x8 b; } pa;
    pa.u[0] = act ? f2bf(pf0.x) : 0;
    pa.u[1] = act ? f2bf(pf0.y) : 0;
    pa.u[2] = act ? f2bf(pf0.z) : 0;
    pa.u[3] = act ? f2bf(pf0.w) : 0;
    pa.u[4] = act ? f2bf(pf1.x) : 0;
    pa.u[5] = act ? f2bf(pf1.y) : 0;
    pa.u[6] = act ? f2bf(pf1.z) : 0;
    pa.u[7] = act ? f2bf(pf1.w) : 0;

    float o4[4][4];
    #pragma unroll
    for (int c4 = 0; c4 < 4; ++c4) {
        const int d = c4 * 16 + m;
        bf16x8 vf = *(const bf16x8*)(sVt + d * 24 + (d >> 3) * 8 + (q & 1) * 8);
        f32x4 o = {0.f, 0.f, 0.f, 0.f};
        o = __builtin_amdgcn_mfma_f32_16x16x32_bf16(pa.b, vf, o, 0, 0, 0);
        #pragma unroll
        for (int r = 0; r < 4; ++r) o4[c4][r] = o[r];
    }
    __syncthreads();

    unsigned short* sO = sVt;
    #pragma unroll
    for (int c4 = 0; c4 < 4; ++c4) {
        #pragma unroll
        for (int r = 0; r < 4; ++r) {
            int col = (q * 4 + r) * 64 + c4 * 16 + m;
            sO[col + ((col >> 6) << 3)] = f2bf(o4[c4][r]);
        }
    }
    __syncthreads();

    const size_t tileBase = (size_t)(row >> 4) * 32 * 512;
    const int fr_tok = row & 15;
    #pragma unroll
    for (int t = 0; t < 2; ++t) {
        int j = t * 64 + lane;
        uint4 val = *(const uint4*)(sO + j * 8 + ((j >> 3) << 3));
        *(uint4*)(attP + tileBase + (size_t)(j >> 2) * 512
                  + ((j & 3) * 16 + fr_tok) * 8) = val;
    }
}

extern "C" void kernel_launch(void* const* d_in, const int* in_sizes, int n_in,
                              void* d_out, int out_size, void* d_ws, size_t ws_size,
                              hipStream_t stream) {
    const float* x    = (const float*)d_in[0];
    const float* Wqkv = (const float*)d_in[1];
    const float* bqkv = (const float*)d_in[2];
    const float* Wout = (const float*)d_in[3];
    const float* bout = (const float*)d_in[4];
    float* out = (float*)d_out;

    // workspace: xp 32M | Wqkv_p 6M | Wout_p 2M | qkv 96M = ~136 MB
    char* ws = (char*)d_ws;
    unsigned short* xp   = (unsigned short*)ws;                 ws += (size_t)Mc * Kc * 2;
    unsigned short* Wqkp = (unsigned short*)ws;                 ws += (size_t)N1c * Kc * 2;
    unsigned short* Wop  = (unsigned short*)ws;                 ws += (size_t)Cc * Kc * 2;
    unsigned short* qkv  = (unsigned short*)ws;

    // one-time opt-in to 128 KB dynamic LDS; fall back to 128^2 GEMM on failure
    constexpr int DYN_LDS = 2 * 64 * 512 * 2;   // 131072 B
    static int big_ok = -1;
    if (big_ok < 0) {
        hipError_t e1 = hipFuncSetAttribute(
            reinterpret_cast<const void*>(gemm256_kernel<true>),
            hipFuncAttributeMaxDynamicSharedMemorySize, DYN_LDS);
        hipError_t e2 = hipFuncSetAttribute(
            reinterpret_cast<const void*>(gemm256_kernel<false>),
            hipFuncAttributeMaxDynamicSharedMemorySize, DYN_LDS);
        big_ok = (e1 == hipSuccess && e2 == hipSuccess) ? 1 : 0;
    }

    // 1) prep: x -> packed fragments; weights -> packed fragments (transposed)
    prep_kernel<<<8192 + 3072 + 1024, 256, 0, stream>>>(x, xp, Wqkv, Wqkp, Wout, Wop);

    // 2) qkv = x @ W_qkv + b_qkv (bf16 row-major out)
    if (big_ok)
        gemm256_kernel<true><<<(Mc / 256) * (N1c / 256), 512, DYN_LDS, stream>>>(
            xp, Wqkp, bqkv, qkv, Mc, N1c, Kc, N1c / 256);
    else
        lds_gemm_kernel<true><<<(N1c / 128) * (Mc / 128), 256, 0, stream>>>(
            xp, Wqkp, bqkv, qkv, Mc, N1c, Kc, N1c / 128);

    // 3) head-axis attention per token (MFMA), writes packed-fragment A (aliases xp)
    attn_mfma_kernel<<<Mc / 4, 256, 0, stream>>>(qkv, xp);

    // 4) out = att @ W_out + b_out (fp32 row-major out)
    if (big_ok)
        gemm256_kernel<false><<<(Mc / 256) * (Cc / 256), 512, DYN_LDS, stream>>>(
            xp, Wop, bout, out, Mc, Cc, Kc, Cc / 256);
    else
        lds_gemm_kernel<false><<<(Cc / 128) * (Mc / 128), 256, 0, stream>>>(
            xp, Wop, bout, out, Mc, Cc, Kc, Cc / 128);
}